// Round 8
// baseline (193.106 us; speedup 1.0000x reference)
//
#include <hip/hip_runtime.h>
#include <math.h>

#define NN 50000
#define NE 800000
#define CD 128
#define PB 3200          // prep blocks (grid-stride)
#define NBLK 1563        // dst bins of 32 nodes (1563*32 = 50016 >= NN)
#define CSTR 1568        // cursor stride per XCD group (16-aligned: line = 16 cursors of one group)
#define SCAP 160         // sub-bin capacity (Poisson(64) expected; P(>160) ~ 1e-25)

typedef __attribute__((ext_vector_type(8))) short short8;
typedef __attribute__((ext_vector_type(4))) float f32x4;

// ---------------- helpers ----------------

__device__ inline unsigned pack2bf(float lo, float hi) {
    unsigned a = __float_as_uint(lo), b = __float_as_uint(hi);
    a = (a + 0x7fffu + ((a >> 16) & 1u)) >> 16;
    b = (b + 0x7fffu + ((b >> 16) & 1u)) & 0xffff0000u;
    return a | b;
}

__device__ inline unsigned short f2bf(float f) {
    unsigned u = __float_as_uint(f);
    return (unsigned short)((u + 0x7fffu + ((u >> 16) & 1u)) >> 16);
}

__device__ inline void fmax8(float* m, uint4 v) {
    m[0] = fmaxf(m[0], __uint_as_float(v.x << 16));
    m[1] = fmaxf(m[1], __uint_as_float(v.x & 0xffff0000u));
    m[2] = fmaxf(m[2], __uint_as_float(v.y << 16));
    m[3] = fmaxf(m[3], __uint_as_float(v.y & 0xffff0000u));
    m[4] = fmaxf(m[4], __uint_as_float(v.z << 16));
    m[5] = fmaxf(m[5], __uint_as_float(v.z & 0xffff0000u));
    m[6] = fmaxf(m[6], __uint_as_float(v.w << 16));
    m[7] = fmaxf(m[7], __uint_as_float(v.w & 0xffff0000u));
}

// ---------------- prep: XCD-local sub-binned edge buckets + bf16 casts --------
// Sub-bin = (dst>>5, blockIdx&7). Cursor lines are touched by one XCD group
// only (dispatch round-robin heuristic) -> L2-local atomics, no cross-XCD
// line ping-pong. Bucket writes are cursor-sequential -> full-line writeback.
// Sub-bin overflow goes to a global list (cap NE -> can never drop an edge).
// Entry word: (src << 6) | (dst & 31).  Overflow word: (src << 16) | dst.

__global__ __launch_bounds__(256) void prep4_k(const int* __restrict__ ei,
                                               const float* __restrict__ x,
                                               const float* __restrict__ W,
                                               int* __restrict__ cur,
                                               int* __restrict__ ovfn,
                                               unsigned* __restrict__ ovf,
                                               unsigned* __restrict__ ent,
                                               unsigned* __restrict__ xb,
                                               unsigned short* __restrict__ wt) {
    int t = threadIdx.x;
    int b = blockIdx.x;
    int tid0 = b * 256 + t;
    int g = b & 7;
    int phase = (b >> 3) & 1;   // stagger roles so atomics overlap streaming

    for (int p = 0; p < 2; p++) {
        if ((p ^ phase) == 0) {
            // edge-bucket slice
            for (int e = tid0; e < NE; e += PB * 256) {
                int d = ei[NE + e];
                int s = ei[e];
                int bin = d >> 5;
                int pos = atomicAdd(&cur[g * CSTR + bin], 1);
                if (pos < SCAP) {
                    ent[(size_t)(g * NBLK + bin) * SCAP + pos] =
                        ((unsigned)s << 6) | (unsigned)(d & 31);
                } else {
                    int op = atomicAdd(ovfn, 1);
                    ovf[op] = ((unsigned)s << 16) | (unsigned)d;
                }
            }
        } else {
            // x -> bf16 slice
            for (int i = tid0; i < NN * CD / 4; i += PB * 256) {
                float4 v = ((const float4*)x)[i];
                uint2 r;
                r.x = pack2bf(v.x, v.y);
                r.y = pack2bf(v.z, v.w);
                ((uint2*)xb)[i] = r;
            }
        }
    }
    // W -> transposed bf16 wt[n][k]
    for (int i = tid0; i < 2 * CD * CD; i += PB * 256) {
        int n = i >> 8, k = i & 255;
        wt[(size_t)n * 256 + k] = f2bf(W[(size_t)k * 128 + n]);
    }
}

// ---------------- fused gather + GEMM: one block = 32 output rows, 4 waves ----
// Phase 0: coalesced read of the block's 8 sub-lists (+ overflow scan, normally
//          empty) -> per-node LDS lists via LDS atomics.
// Phase 1: 16 quarters × 2 nodes each; 8 row-loads in flight per quarter;
//          maxdiff bf16 -> LDS A-tile.
// Phase 2: MFMA GEMM; wave w = row-tile (w&1) × col-half (w>>1).

__global__ __launch_bounds__(256) void fused_k(const unsigned* __restrict__ xb,
                                               const int* __restrict__ cur,
                                               const int* __restrict__ ovfn,
                                               const unsigned* __restrict__ ovf,
                                               const unsigned* __restrict__ ent,
                                               const short* __restrict__ wt,
                                               const float* __restrict__ bias,
                                               float* __restrict__ out) {
    __shared__ unsigned short idx[32][72];   // 64 usable entries, pitch 144 B (16B-aligned rows)
    __shared__ unsigned short amx[32][136];  // maxdiff bf16 A-tile, pitch 272 B
    __shared__ int lcnt[32];
    __shared__ int spill[512];               // per-node-cap overflow (normally empty)
    __shared__ int spn;

    int t = threadIdx.x;
    int b = blockIdx.x;
    int nbase = b * 32;

    if (t < 32) lcnt[t] = 0;
    if (t == 32) spn = 0;
    __syncthreads();

    // ---- phase 0: build per-node lists ----
    for (int g = 0; g < 8; g++) {
        int cnt = min(cur[g * CSTR + b], SCAP);
        const unsigned* base = ent + (size_t)(g * NBLK + b) * SCAP;
        if (t < cnt) {                        // cnt <= 160 < 256: one shot
            unsigned w = base[t];
            int ln = (int)(w & 31u);
            int s = (int)(w >> 6);
            int pos = atomicAdd(&lcnt[ln], 1);
            if (pos < 64) idx[ln][pos] = (unsigned short)s;
            else { int sp = atomicAdd(&spn, 1); if (sp < 512) spill[sp] = (s << 6) | ln; }
        }
    }
    int ovN = min(ovfn[0], NE);               // prep-side overflow (normally 0)
    for (int i = t; i < ovN; i += 256) {
        unsigned w = ovf[i];
        int d = (int)(w & 0xffffu);
        if ((d >> 5) == b) {
            int ln = d & 31;
            int s = (int)(w >> 16);
            int pos = atomicAdd(&lcnt[ln], 1);
            if (pos < 64) idx[ln][pos] = (unsigned short)s;
            else { int sp = atomicAdd(&spn, 1); if (sp < 512) spill[sp] = (s << 6) | ln; }
        }
    }
    __syncthreads();

    // ---- phase 1: segment max, 2 nodes per 16-lane quarter ----
    int w = t >> 6, lane = t & 63;
    int q = lane >> 4, c = lane & 15;
    int sN = min(spn, 512);
#pragma unroll 1
    for (int j = 0; j < 2; j++) {
        int ln = w * 8 + j * 4 + q;
        int node = nbase + ln;
        int cnt = lcnt[ln];
        int lim = min(cnt, 64);
        float m[8];
#pragma unroll
        for (int i = 0; i < 8; i++) m[i] = -INFINITY;

        for (int base = 0; base < lim; base += 8) {
            uint4 pk = *(const uint4*)&idx[ln][base];
            int s0 = (int)(pk.x & 0xffffu), s1 = (int)(pk.x >> 16);
            int s2 = (int)(pk.y & 0xffffu), s3 = (int)(pk.y >> 16);
            int s4 = (int)(pk.z & 0xffffu), s5 = (int)(pk.z >> 16);
            int s6 = (int)(pk.w & 0xffffu), s7 = (int)(pk.w >> 16);
            if (base + 8 <= lim) {            // fast path: 8 loads in flight
                fmax8(m, *(const uint4*)(xb + (size_t)s0 * 64 + c * 4));
                fmax8(m, *(const uint4*)(xb + (size_t)s1 * 64 + c * 4));
                fmax8(m, *(const uint4*)(xb + (size_t)s2 * 64 + c * 4));
                fmax8(m, *(const uint4*)(xb + (size_t)s3 * 64 + c * 4));
                fmax8(m, *(const uint4*)(xb + (size_t)s4 * 64 + c * 4));
                fmax8(m, *(const uint4*)(xb + (size_t)s5 * 64 + c * 4));
                fmax8(m, *(const uint4*)(xb + (size_t)s6 * 64 + c * 4));
                fmax8(m, *(const uint4*)(xb + (size_t)s7 * 64 + c * 4));
            } else {
                if (base + 0 < lim) fmax8(m, *(const uint4*)(xb + (size_t)s0 * 64 + c * 4));
                if (base + 1 < lim) fmax8(m, *(const uint4*)(xb + (size_t)s1 * 64 + c * 4));
                if (base + 2 < lim) fmax8(m, *(const uint4*)(xb + (size_t)s2 * 64 + c * 4));
                if (base + 3 < lim) fmax8(m, *(const uint4*)(xb + (size_t)s3 * 64 + c * 4));
                if (base + 4 < lim) fmax8(m, *(const uint4*)(xb + (size_t)s4 * 64 + c * 4));
                if (base + 5 < lim) fmax8(m, *(const uint4*)(xb + (size_t)s5 * 64 + c * 4));
                if (base + 6 < lim) fmax8(m, *(const uint4*)(xb + (size_t)s6 * 64 + c * 4));
                if (base + 7 < lim) fmax8(m, *(const uint4*)(xb + (size_t)s7 * 64 + c * 4));
            }
        }
        // per-node-cap spill (normally sN == 0)
        for (int i = 0; i < sN; i++) {
            int sw = spill[i];
            if ((sw & 63) == ln)
                fmax8(m, *(const uint4*)(xb + (size_t)(sw >> 6) * 64 + c * 4));
        }
        uint4 r = make_uint4(0u, 0u, 0u, 0u);
        if (cnt > 0) {                        // implies node < NN
            uint4 xd = *(const uint4*)(xb + (size_t)node * 64 + c * 4);
            float d0 = m[0] - __uint_as_float(xd.x << 16);
            float d1 = m[1] - __uint_as_float(xd.x & 0xffff0000u);
            float d2 = m[2] - __uint_as_float(xd.y << 16);
            float d3 = m[3] - __uint_as_float(xd.y & 0xffff0000u);
            float d4 = m[4] - __uint_as_float(xd.z << 16);
            float d5 = m[5] - __uint_as_float(xd.z & 0xffff0000u);
            float d6 = m[6] - __uint_as_float(xd.w << 16);
            float d7 = m[7] - __uint_as_float(xd.w & 0xffff0000u);
            r.x = pack2bf(d0, d1);
            r.y = pack2bf(d2, d3);
            r.z = pack2bf(d4, d5);
            r.w = pack2bf(d6, d7);
        }
        *(uint4*)&amx[ln][c * 8] = r;
    }
    __syncthreads();

    // ---- phase 2: MFMA GEMM (verified round-3 layout) ----
    int mm = lane & 15, g4 = lane >> 4;
    int rt = w & 1, ch = w >> 1;
    int r0 = nbase + rt * 16;
    int row = r0 + mm;
    bool rowok = row < NN;

    f32x4 acc[4];
#pragma unroll
    for (int ct = 0; ct < 4; ct++) {
        float bv = bias[ch * 64 + ct * 16 + mm];
        acc[ct] = (f32x4){bv, bv, bv, bv};
    }

    const short* xbs = (const short*)xb;
#pragma unroll
    for (int kc = 0; kc < 8; kc++) {
        int k0 = kc * 32;
        short8 a;
        if (kc < 4) {
            a = (short8){0, 0, 0, 0, 0, 0, 0, 0};
            if (rowok) a = *(const short8*)(xbs + (size_t)row * 128 + k0 + g4 * 8);
        } else {
            a = *(const short8*)&amx[rt * 16 + mm][(k0 - 128) + g4 * 8];
        }
#pragma unroll
        for (int ct = 0; ct < 4; ct++) {
            short8 bb = *(const short8*)(wt + (size_t)(ch * 64 + ct * 16 + mm) * 256 + k0 + g4 * 8);
            acc[ct] = __builtin_amdgcn_mfma_f32_16x16x32_bf16(a, bb, acc[ct], 0, 0, 0);
        }
    }

#pragma unroll
    for (int ct = 0; ct < 4; ct++) {
#pragma unroll
        for (int i = 0; i < 4; i++) {
            int rr = r0 + g4 * 4 + i;
            if (rr < NN) out[(size_t)rr * 128 + ch * 64 + ct * 16 + mm] = acc[ct][i];
        }
    }
}

// ---------------- launch ----------------

extern "C" void kernel_launch(void* const* d_in, const int* in_sizes, int n_in,
                              void* d_out, int out_size, void* d_ws, size_t ws_size,
                              hipStream_t stream) {
    const float* x = (const float*)d_in[0];
    const int* ei = (const int*)d_in[1];     // (2, E): [0..E)=src, [E..2E)=dst
    const float* W = (const float*)d_in[2];  // (256, 128) row-major
    const float* bias = (const float*)d_in[3];
    float* out = (float*)d_out;

    // Workspace layout (ints). Total = 6,029,584 ints = 24.12 MB.
    int* wsi = (int*)d_ws;
    int* cur   = wsi;                               // 8*CSTR = 12544 ints
    int* ovfn  = wsi + 12544;                       // 16 ints (1 used)
    unsigned* ovf = (unsigned*)(wsi + 12560);       // 800000 (cap NE: can never drop)
    unsigned* ent = (unsigned*)(wsi + 812560);      // 8*NBLK*SCAP = 2,000,640
    unsigned* xb  = (unsigned*)(wsi + 2813200);     // 3,200,000 (16B-aligned)
    unsigned short* wt = (unsigned short*)(wsi + 6013200);  // 32768 ush = 16384 ints

    hipMemsetAsync(cur, 0, (8 * CSTR + 16) * sizeof(int), stream);  // cur + ovfn

    prep4_k<<<PB, 256, 0, stream>>>(ei, x, W, cur, ovfn, ovf, ent, xb, wt);
    fused_k<<<NBLK, 256, 0, stream>>>(xb, cur, ovfn, ovf, ent, (const short*)wt,
                                      bias, out);
}